// Round 1
// baseline (255.433 us; speedup 1.0000x reference)
//
#include <hip/hip_runtime.h>
#include <stdint.h>

#define BB     64
#define CC     12
#define LL     2048
#define KERNSZ 9
#define KK     8     // kernels per group
#define GG     32    // groups per branch (_G)
#define NPER   6
#define NDIL   8
#define PAD    256   // halo covers D<=64 exactly; D=128 uses clamped taps
#define MAIN   2048
#define BUFSZ  (PAD + MAIN + PAD)   // 2560 floats = 10 KB per wave
#define WPB    4                    // 4 waves -> 40 KB LDS -> 4 blocks/CU (16 waves)

typedef float f2 __attribute__((ext_vector_type(2)));
typedef float f4 __attribute__((ext_vector_type(4)));

// acc.{lo,hi} += t.lo * w.{lo,hi}   (tap broadcast via op_sel_hi[0]=0;
// weights are a wave-uniform SGPR pair -> no VGPR replication, no spill)
__device__ __forceinline__ void pk_fma_bcast(f2& acc, const f2& t, uint64_t wpair) {
    asm("v_pk_fma_f32 %0, %1, %2, %0 op_sel:[0,0,0] op_sel_hi:[0,1,1]"
        : "+v"(acc) : "v"(t), "s"(wpair));
}
__device__ __forceinline__ f2 pk_mul_bcast(const f2& t, uint64_t wpair) {
    f2 d;
    asm("v_pk_mul_f32 %0, %1, %2 op_sel:[0,0] op_sel_hi:[0,1]"
        : "=v"(d) : "v"(t), "s"(wpair));
    return d;
}

// Phase 2, specialized on compile-time dilation D (tap offsets are immediates).
template <int D>
__device__ __forceinline__ void run_phase2(
    const float* __restrict__ sel, int lane, int dif,
    const uint64_t (&wp)[4][KERNSZ], float (&accM)[KK], uint32_t (&accN)[KK])
{
    const float NANF = __uint_as_float(0x7fc00000u);

    #pragma unroll 2
    for (int q = 0; q < 32; ++q) {
        const int pos = q * 64 + lane;

        f2 t[KERNSZ];                          // only .x meaningful; f2 forces
                                               // even-aligned VGPR pair for asm
        if constexpr (D == 128) {
            // halo is only 256; clamp OOB taps into the zeroed pads -> tap=0,
            // identical contribution to what 512-wide zero padding gave.
            #pragma unroll
            for (int j = 0; j < KERNSZ; ++j) {
                int off = pos + (j - 4) * D;
                if (j < 4) off = (off < -PAD) ? -PAD : off;
                if (j > 4) off = (off > MAIN + PAD - 1) ? (MAIN + PAD - 1) : off;
                t[j].x = sel[off];
            }
        } else {
            const float* p = sel + pos - 4 * D;   // pads make all 9 taps valid
            #pragma unroll
            for (int j = 0; j < KERNSZ; ++j)
                t[j].x = p[j * D];
        }

        f2 v2[4];                              // (v0,v1)(v2,v3)(v4,v5)(v6,v7)
        #pragma unroll
        for (int c = 0; c < 4; ++c)
            v2[c] = pk_mul_bcast(t[0], wp[c][0]);
        #pragma unroll
        for (int j = 1; j < KERNSZ; ++j)
            #pragma unroll
            for (int c = 0; c < 4; ++c)
                pk_fma_bcast(v2[c], t[j], wp[c][j]);

        float v[KK] = { v2[0].x, v2[0].y, v2[1].x, v2[1].y,
                        v2[2].x, v2[2].y, v2[3].x, v2[3].y };

        // v_max3/v_min3-shaped trees: 4 instrs each instead of 7
        float m1 = fmaxf(fmaxf(v[0], v[1]), v[2]);
        float m2 = fmaxf(fmaxf(v[3], v[4]), v[5]);
        float m3 = fmaxf(fmaxf(v[6], v[7]), m1);
        float mv = fmaxf(m2, m3);
        float n1 = fminf(fminf(v[0], v[1]), v[2]);
        float n2 = fminf(fminf(v[3], v[4]), v[5]);
        float n3 = fminf(fminf(v[6], v[7]), n1);
        float nv = fminf(n2, n3);

        // only invalid output position: pos==2047 on diff branch.
        // NaN never compares equal -> contributes nothing below.
        if (dif && q == 31) {
            if (lane == 63) { mv = NANF; nv = NANF; }
        }

        #pragma unroll
        for (int k = 0; k < KK; ++k) {
            accM[k] += (v[k] == mv) ? v[k] : 0.0f;   // exact: mv bit-equals winner
            accN[k] += (v[k] == nv) ? 1u : 0u;       // v_cmp + v_addc
        }
    }
}

__global__ __launch_bounds__(256, 4) void hydra_kernel(
    const float* __restrict__ X,    // [B, C, L]
    const float* __restrict__ W,    // [NDIL, 2, KK*GG, 1, KERNSZ]
    const int*   __restrict__ I,    // [NDIL, 2, GG, NPER]
    float*       __restrict__ out)  // [B, 8192]
{
    __shared__ float lds[WPB][BUFSZ];

    const int tid  = threadIdx.x;
    const int wave = tid >> 6;
    const int lane = tid & 63;
    const int wid  = blockIdx.x * WPB + wave;   // 0..32767
    // task decode: wid = b*512 + di*64 + dif*32 + g
    const int b   = wid >> 9;
    const int r   = wid & 511;
    const int di  = r >> 6;
    const int r2  = r & 63;
    const int dif = r2 >> 5;
    const int g   = r2 & 31;

    float* buf = lds[wave];
    float* sel = buf + PAD;

    // ---- zero halo pads (vectorized: 64 lanes x float4 = 256 floats) ----
    {
        f4 z = {0.0f, 0.0f, 0.0f, 0.0f};
        ((f4*)buf)[lane]                        = z;   // left pad
        ((f4*)(buf + PAD + MAIN))[lane]         = z;   // right pad
    }

    // ---- phase 1: channel-subset sum S into sel[0..2047] (dwordx4 loads) ----
    const int* Ig = I + ((size_t)((di * 2 + dif) * GG + g)) * NPER;
    const float* xb = X + (size_t)b * CC * LL;
    const f4* c0 = (const f4*)(xb + Ig[0] * LL);
    const f4* c1 = (const f4*)(xb + Ig[1] * LL);
    const f4* c2 = (const f4*)(xb + Ig[2] * LL);
    const f4* c3 = (const f4*)(xb + Ig[3] * LL);
    const f4* c4 = (const f4*)(xb + Ig[4] * LL);
    const f4* c5 = (const f4*)(xb + Ig[5] * LL);
    f4* sel4 = (f4*)sel;

    #pragma unroll 2
    for (int q = 0; q < 8; ++q) {
        int idx = q * 64 + lane;                  // float4 index, 512 quads total
        f4 s = (c0[idx] + c1[idx]) + (c2[idx] + c3[idx]) + (c4[idx] + c5[idx]);
        sel4[idx] = s;
    }

    if (dif) {
        // in-place wave-synchronous forward diff, vectorized. Per-wave LDS ops
        // are in program order: all lanes' reads of iteration q issue before
        // its writes; lane l's extra scalar read at idx*4+4 targets data
        // written only later (lane l+1 this iter, or region of iter q+1).
        #pragma unroll 2
        for (int q = 0; q < 8; ++q) {
            int idx = q * 64 + lane;              // quad index
            f4 a  = sel4[idx];
            float an = sel[idx * 4 + 4];          // sel[2048] is the zeroed pad
            f4 v;
            v.x = a.y - a.x;
            v.y = a.z - a.y;
            v.z = a.w - a.z;
            v.w = (idx == 511) ? 0.0f : (an - a.w);   // pos 2047 -> 0
            sel4[idx] = v;
        }
    }

    // ---- weights: wave-uniform scalar loads, packed into SGPR pairs ----
    const float* Wg = W + (size_t)((di * 2 + dif) * (KK * GG) + g * KK) * KERNSZ;
    uint64_t wp[4][KERNSZ];   // wp[c][j] = (w[2c][j], w[2c+1][j])
    #pragma unroll
    for (int c = 0; c < 4; ++c)
        #pragma unroll
        for (int j = 0; j < KERNSZ; ++j) {
            uint32_t lo = __float_as_uint(Wg[(2 * c)     * KERNSZ + j]);
            uint32_t hi = __float_as_uint(Wg[(2 * c + 1) * KERNSZ + j]);
            wp[c][j] = (uint64_t)lo | ((uint64_t)hi << 32);
        }

    float    accM[KK];
    uint32_t accN[KK];
    #pragma unroll
    for (int k = 0; k < KK; ++k) { accM[k] = 0.0f; accN[k] = 0u; }

    switch (di) {   // block-uniform branch
        case 0: run_phase2<1>  (sel, lane, dif, wp, accM, accN); break;
        case 1: run_phase2<2>  (sel, lane, dif, wp, accM, accN); break;
        case 2: run_phase2<4>  (sel, lane, dif, wp, accM, accN); break;
        case 3: run_phase2<8>  (sel, lane, dif, wp, accM, accN); break;
        case 4: run_phase2<16> (sel, lane, dif, wp, accM, accN); break;
        case 5: run_phase2<32> (sel, lane, dif, wp, accM, accN); break;
        case 6: run_phase2<64> (sel, lane, dif, wp, accM, accN); break;
        default: run_phase2<128>(sel, lane, dif, wp, accM, accN); break;
    }

    // ---- wave butterfly reduction of the 16 accumulators ----
    float* o = out + (size_t)b * 8192 + (size_t)((di * 2 + dif) * 2) * 256 + g * KK;
    #pragma unroll
    for (int k = 0; k < KK; ++k) {
        float a = accM[k];
        unsigned c = accN[k];
        #pragma unroll
        for (int off = 32; off > 0; off >>= 1) {
            a += __shfl_xor(a, off, 64);
            c += __shfl_xor(c, off, 64);
        }
        if (lane == 0) {
            o[k]       = a;          // count_max block (which=0)
            o[256 + k] = (float)c;   // count_min block (which=1)
        }
    }
}

extern "C" void kernel_launch(void* const* d_in, const int* in_sizes, int n_in,
                              void* d_out, int out_size, void* d_ws, size_t ws_size,
                              hipStream_t stream) {
    const float* X = (const float*)d_in[0];
    const float* W = (const float*)d_in[1];
    const int*   I = (const int*)d_in[2];
    float* out = (float*)d_out;

    const int total_waves = BB * NDIL * 2 * GG;       // 32768
    const int blocks = total_waves / WPB;             // 8192
    hydra_kernel<<<blocks, 256, 0, stream>>>(X, W, I, out);
}